// Round 3
// baseline (303.144 us; speedup 1.0000x reference)
//
#include <hip/hip_runtime.h>

// PseudoImageScatter: img[f, y, x] = pillar_features[p, f], last pillar wins.
// Pass 1: winner[y*W+x] = atomicMax(pillar idx)  (last-wins == max idx)
// Pass 2: burst-oriented transpose. Block = 1024 cells, 16 passes of 4
//         features. Per pass each of the 4 waves writes ONE plane as a
//         4 KB sequential burst.
//   Changes vs round 2 (which was ~neutral vs round 1):
//   - TILE 2048 -> 1024: 1024 blocks = 4 blocks/CU = 4 waves/SIMD (was 2).
//     More resident waves to hide DS latency + barrier rendezvous under the
//     store stream.
//   - Ping-pong LDS: stage pass p into buf[p&1]. Readers of buf[(p+1)&1]
//     finished before the pass-p barrier on every wave, so staging p+1 needs
//     no second barrier -> ONE bar_lds per pass (16 vs 32 rendezvous).
//   - Barriers remain lgkmcnt(0)+s_barrier only (never drain vmcnt; NT
//     stores and prefetch loads stay in flight).
//   - Branchless zero cells: gather row max(wp,0), select 0.

constexpr int H    = 1024;
constexpr int W    = 1024;
constexpr int HW   = H * W;
constexpr int NF   = 64;
constexpr int TILE = 1024;          // cells per block
constexpr int CPT  = TILE / 256;    // cells per thread = 4
constexpr int FP   = 4;             // features per pass (== waves per block)
constexpr int NP   = NF / FP;       // 16 passes

typedef float nt4 __attribute__((ext_vector_type(4)));

__global__ void winner_kernel(const int* __restrict__ coords,
                              int* __restrict__ winner, int np) {
    int p = blockIdx.x * blockDim.x + threadIdx.x;
    if (p >= np) return;
    int y = coords[p * 3 + 1];
    int x = coords[p * 3 + 2];
    if ((unsigned)x < (unsigned)W && (unsigned)y < (unsigned)H) {
        atomicMax(winner + (y * W + x), p);   // device-scope, cross-XCD safe
    }
}

// LDS-only barrier: order my DS ops, then rendezvous. Does NOT drain vmcnt —
// nontemporal stores / prefetch loads stay in flight across phases.
__device__ __forceinline__ void bar_lds() {
    asm volatile("s_waitcnt lgkmcnt(0)" ::: "memory");
    __builtin_amdgcn_s_barrier();
}

__global__ void __launch_bounds__(256) fill_kernel(const float* __restrict__ feat,
                                                   const int* __restrict__ winner,
                                                   float* __restrict__ out) {
    __shared__ float lds[2][FP * TILE];       // 2 x 16 KiB = 32 KiB -> 4 blocks/CU
    const int t  = threadIdx.x;
    const int wv = t >> 6;                    // wave id 0..3 -> feature-in-pass
    const int l  = t & 63;                    // lane
    const int tb = blockIdx.x * TILE;

    const float4 z4 = make_float4(0.f, 0.f, 0.f, 0.f);

    // Per-thread cells: cc = k*256 + t (lane-contiguous per k chunk).
    const float4* row[CPT];
    bool          ok[CPT];
#pragma unroll
    for (int k = 0; k < CPT; ++k) {
        int wp = winner[tb + k * 256 + t];    // coalesced
        ok[k]  = wp >= 0;
        row[k] = (const float4*)(feat + (size_t)max(wp, 0) * NF);
    }

    float4 g[2][CPT];                         // double-buffered gather regs
#pragma unroll
    for (int k = 0; k < CPT; ++k) {           // prefetch pass 0 (features 0..3)
        float4 v = row[k][0];
        g[0][k] = ok[k] ? v : z4;
    }

#pragma unroll
    for (int p = 0; p < NP; ++p) {            // fully unrolled -> static g idx
        const int c = p & 1;

        // ---- stage into buf c: lds[c][q*TILE + cc] = feature (4p+q) of cc.
        // Lane-contiguous b32 writes: bank = cc%32, 2-way alias = free.
        // Safe without a pre-barrier: every wave's reads of buf c (pass p-2)
        // completed before the pass p-1 barrier.
#pragma unroll
        for (int k = 0; k < CPT; ++k) {
            const int cc = k * 256 + t;
            lds[c][0 * TILE + cc] = g[c][k].x;
            lds[c][1 * TILE + cc] = g[c][k].y;
            lds[c][2 * TILE + cc] = g[c][k].z;
            lds[c][3 * TILE + cc] = g[c][k].w;
        }
        bar_lds();                            // the ONLY barrier this pass

        // ---- prefetch next pass's gathers (hidden under the store burst)
        if (p + 1 < NP) {
#pragma unroll
            for (int k = 0; k < CPT; ++k) {
                float4 v = row[k][p + 1];
                g[c ^ 1][k] = ok[k] ? v : z4;
            }
        }

        // ---- store burst: wave wv owns plane f = 4p + wv, writes
        // cells tb..tb+1023 as 4 consecutive 1 KiB nt4 stores = 4 KiB seq.
        float* dst = out + (size_t)(p * FP + wv) * HW + tb;
#pragma unroll
        for (int j = 0; j < CPT; ++j) {
            nt4 v = *(const nt4*)&lds[c][wv * TILE + j * 256 + l * 4];
            __builtin_nontemporal_store(v, (nt4*)(dst + j * 256 + l * 4));
        }
    }
}

extern "C" void kernel_launch(void* const* d_in, const int* in_sizes, int n_in,
                              void* d_out, int out_size, void* d_ws, size_t ws_size,
                              hipStream_t stream) {
    const float* feat   = (const float*)d_in[0];
    const int*   coords = (const int*)d_in[1];
    float*       out    = (float*)d_out;
    int np = in_sizes[1] / 3;

    int* winner = (int*)d_ws;   // HW ints = 4 MiB scratch

    (void)hipMemsetAsync(winner, 0xFF, (size_t)HW * sizeof(int), stream);  // winner := -1
    winner_kernel<<<(np + 255) / 256, 256, 0, stream>>>(coords, winner, np);
    fill_kernel<<<HW / TILE, 256, 0, stream>>>(feat, winner, out);
}